// Round 9
// baseline (309.890 us; speedup 1.0000x reference)
//
#include <hip/hip_runtime.h>
#include <hip/hip_bf16.h>
#include <cstdint>

// Problem constants
#define B_ 4
#define N_ 2048
#define C_ 768
#define H_ 12
#define D_ 64
// SCALE = D^-0.5 = 0.125; folded exp2 scale = 0.125 * log2(e)
#define QSCALE 0.18033688011112042f

// s_waitcnt immediates (gfx9 encoding): vmcnt[3:0]|expcnt[6:4]|lgkmcnt[11:8]|vmcnt[5:4]@[15:14]
#define WAIT_VM0 0x0F70   // vmcnt(0), no lgkm/exp wait
#define WAIT_VM4 0x0F74   // vmcnt(4)
#define WAIT_VM6 0x0F76   // vmcnt(6)
#define WAIT_VM8 0x0F78   // vmcnt(8)

typedef __bf16 bf16x8 __attribute__((ext_vector_type(8)));
typedef float f32x4 __attribute__((ext_vector_type(4)));

__device__ __forceinline__ unsigned f2bs(float x) {
  unsigned u = __builtin_bit_cast(unsigned, x);
  return (u + 0x7fffu + ((u >> 16) & 1u)) >> 16;
}

__device__ __forceinline__ bf16x8 ldb8(const unsigned short* p) {
  return __builtin_bit_cast(bf16x8, *(const uint4*)p);
}

__device__ __forceinline__ f32x4 mfma16(bf16x8 a, bf16x8 b, f32x4 c) {
  return __builtin_amdgcn_mfma_f32_16x16x32_bf16(a, b, c, 0, 0, 0);
}

// async global->LDS, 16B/lane; deposits at lds + lane*16 (wave-uniform base).
__device__ __forceinline__ void async16(const unsigned short* g, unsigned short* l) {
  __builtin_amdgcn_global_load_lds(
      (const __attribute__((address_space(1))) unsigned int*)g,
      (__attribute__((address_space(3))) unsigned int*)l, 16, 0, 0);
}

// ---------------- fused prep: x/W f32->bf16 casts + uc row means ----------------
__global__ void prep_kernel(
    const float* __restrict__ xq, const float* __restrict__ xk,
    const float* __restrict__ xv, const float* __restrict__ xu,
    const float* __restrict__ Wq, const float* __restrict__ Wk,
    const float* __restrict__ Wv, const float* __restrict__ Wp,
    unsigned short* __restrict__ dxq, unsigned short* __restrict__ dxk,
    unsigned short* __restrict__ dxv,
    unsigned short* __restrict__ dwq, unsigned short* __restrict__ dwk,
    unsigned short* __restrict__ dwv, unsigned short* __restrict__ dwp,
    float* __restrict__ uc) {
  const int id = blockIdx.x;
  if (id < 18432) {
    const float* s = (id < 6144) ? xq : (id < 12288) ? xk : xv;
    unsigned short* d = (id < 6144) ? dxq : (id < 12288) ? dxk : dxv;
    int i = ((id % 6144) * 256 + threadIdx.x) * 4;
    float4 v = *(const float4*)(s + i);
    ushort4 h;
    h.x = (unsigned short)f2bs(v.x); h.y = (unsigned short)f2bs(v.y);
    h.z = (unsigned short)f2bs(v.z); h.w = (unsigned short)f2bs(v.w);
    *(ushort4*)(d + i) = h;
  } else if (id < 20736) {
    int sub = id - 18432;
    int which = sub / 576;
    const float* s = (which == 0) ? Wq : (which == 1) ? Wk : (which == 2) ? Wv : Wp;
    unsigned short* d = (which == 0) ? dwq : (which == 1) ? dwk : (which == 2) ? dwv : dwp;
    int i = ((sub % 576) * 256 + threadIdx.x) * 4;
    float4 v = *(const float4*)(s + i);
    ushort4 h;
    h.x = (unsigned short)f2bs(v.x); h.y = (unsigned short)f2bs(v.y);
    h.z = (unsigned short)f2bs(v.z); h.w = (unsigned short)f2bs(v.w);
    *(ushort4*)(d + i) = h;
  } else {
    int sub = id - 20736;
    int w = threadIdx.x >> 6, lane = threadIdx.x & 63;
    int row = sub * 4 + w;
    const float* p = xu + (size_t)row * C_;
    float s = 0.f;
#pragma unroll
    for (int i = 0; i < 3; ++i) {
      float4 v = *(const float4*)(p + (i * 64 + lane) * 4);
      s += v.x + v.y + v.z + v.w;
    }
#pragma unroll
    for (int off = 1; off < 64; off <<= 1) s += __shfl_xor(s, off);
    if (lane == 0) uc[row] = s * (1.f / 768.f);
  }
}

// ---------------- double-buffered async GEMM mainloop (128x128, BK=64) -------------
// Stage layout: 128 rows x 8 granules (16B), granule slot = g ^ (row&7) (XOR swizzle
// keeps async16 deposits contiguous AND makes b128 frag reads 2-way = free).
// Pipeline: prologue 2 stages; per iter: vmcnt(8)+s_barrier -> compute buf p ->
// s_barrier -> issue stage si+2 into buf p. No vmcnt(0) inside the loop.
__device__ __forceinline__ void gemm_mainloop_db(
    const unsigned short* __restrict__ A, const unsigned short* __restrict__ W,
    int m0, int n0, unsigned short* Ab, unsigned short* Bb,   // each 2*8192 shorts
    int tid, int wm, int wn, int quad, int id15, f32x4 (*acc)[4]) {
  const int wb = tid & 192;
  const unsigned short* ap[4];
  const unsigned short* bp[4];
  int dst[4];
#pragma unroll
  for (int s = 0; s < 4; ++s) {
    int g = s * 256 + tid;
    int row = g >> 3;
    int gs = (g & 7) ^ (row & 7);
    ap[s] = A + (size_t)(m0 + row) * C_ + gs * 8;
    bp[s] = W + (size_t)(n0 + row) * C_ + gs * 8;
    dst[s] = (s * 256 + wb) * 8;
  }
  auto issue = [&](int p, int si) {
    int kt = (si >= 12 ? si - 12 : si) * 64;
#pragma unroll
    for (int s = 0; s < 4; ++s) async16(ap[s] + kt, Ab + p * 8192 + dst[s]);
#pragma unroll
    for (int s = 0; s < 4; ++s) async16(bp[s] + kt, Bb + p * 8192 + dst[s]);
  };
  issue(0, 0);
  issue(1, 1);
  const int sw0 = (quad ^ (id15 & 7)) * 8;
  const int sw1 = ((4 + quad) ^ (id15 & 7)) * 8;

  for (int si = 0; si < 12; ++si) {
    const int p = si & 1;
    __builtin_amdgcn_sched_barrier(0);
    __builtin_amdgcn_s_waitcnt(WAIT_VM8);
    __builtin_amdgcn_s_barrier();
    __builtin_amdgcn_sched_barrier(0);

    const unsigned short* Ap = Ab + p * 8192;
    const unsigned short* Bp = Bb + p * 8192;
#pragma unroll
    for (int kk = 0; kk < 2; ++kk) {
      const int sw = kk ? sw1 : sw0;
      bf16x8 af[4], bfr[4];
#pragma unroll
      for (int i = 0; i < 4; ++i)
        af[i]  = ldb8(Ap + (wm + i * 16 + id15) * 64 + sw);
#pragma unroll
      for (int j = 0; j < 4; ++j)
        bfr[j] = ldb8(Bp + (wn + j * 16 + id15) * 64 + sw);
#pragma unroll
      for (int i = 0; i < 4; ++i)
#pragma unroll
        for (int j = 0; j < 4; ++j)
          acc[i][j] = mfma16(af[i], bfr[j], acc[i][j]);
    }

    __builtin_amdgcn_sched_barrier(0);
    __builtin_amdgcn_s_barrier();
    __builtin_amdgcn_sched_barrier(0);
    issue(p, si + 2);             // si>=10 wraps to stages 0/1 (L2-hot dummy)
  }
  __builtin_amdgcn_s_waitcnt(WAIT_VM0);   // drain before LDS reuse / kernel end
}

// ---------------- fused QKV projection (XCD-swizzled, 1152 blocks) ----------------
#define TSTR 136
__global__ __launch_bounds__(256, 2) void gemm_qkv(
    const unsigned short* __restrict__ xq, const unsigned short* __restrict__ xk,
    const unsigned short* __restrict__ xv,
    const unsigned short* __restrict__ wq, const unsigned short* __restrict__ wk,
    const unsigned short* __restrict__ wv,
    unsigned short* __restrict__ oq, unsigned short* __restrict__ ok,
    unsigned short* __restrict__ ov, const float* __restrict__ uc) {
  __shared__ __align__(16) unsigned short Lds[32768];   // 64 KB: Ab|Bb, aliased by S
  unsigned short* Ab = Lds;
  unsigned short* Bb = Lds + 16384;
  const int tid = threadIdx.x;
  const int w = tid >> 6, lane = tid & 63, quad = lane >> 4, id15 = lane & 15;
  const int wm = (w >> 1) << 6, wn = (w & 1) << 6;
  const int id = blockIdx.x;
  const int xcd = id & 7, slot = id >> 3;
  const int n0 = (slot % 6) << 7;
  const int gz = xcd * 24 + slot / 6;
  const int z = gz >> 6, m0 = (gz & 63) << 7;

  const unsigned short* A = (z == 0) ? xq : (z == 1) ? xk : xv;
  const unsigned short* W = (z == 0) ? wq : (z == 1) ? wk : wv;

  f32x4 acc[4][4] = {};
  gemm_mainloop_db(A, W, m0, n0, Ab, Bb, tid, wm, wn, quad, id15, acc);

  if (z == 2) {
    __syncthreads();                       // all waves drained; safe to reuse Lds
    unsigned short* S = Lds;
#pragma unroll
    for (int i = 0; i < 4; ++i)
#pragma unroll
      for (int j = 0; j < 4; ++j) {
        uint2 u;
        u.x = f2bs(acc[i][j][0]) | (f2bs(acc[i][j][1]) << 16);
        u.y = f2bs(acc[i][j][2]) | (f2bs(acc[i][j][3]) << 16);
        *(uint2*)&S[(wn + j * 16 + id15) * TSTR + wm + i * 16 + quad * 4] = u;
      }
    __syncthreads();
    const int b = m0 >> 11, nb = m0 & (N_ - 1);
#pragma unroll
    for (int s = 0; s < 8; ++s) {
      int c = s * 256 + tid;
      int row = c >> 4, o = (c & 15) << 3;
      *(uint4*)(ov + (size_t)(b * C_ + n0 + row) * N_ + nb + o) = *(const uint4*)&S[row * TSTR + o];
    }
    return;
  }

#pragma unroll
  for (int i = 0; i < 4; ++i) {
#pragma unroll
    for (int j = 0; j < 4; ++j) {
#pragma unroll
      for (int r = 0; r < 4; ++r) {
        int gm = m0 + wm + i * 16 + quad * 4 + r;
        int gn = n0 + wn + j * 16 + id15;
        float v = acc[i][j][r];
        if (z == 0) {
          v *= QSCALE * uc[gm];
          oq[(size_t)gm * C_ + gn] = (unsigned short)f2bs(v);
        } else {
          ok[(size_t)gm * C_ + gn] = (unsigned short)f2bs(v);
        }
      }
    }
  }
}

// ---------------- output projection: 64x128 tile, double-buffered pipeline ---------
__global__ __launch_bounds__(256, 3) void gemm_out(
    const unsigned short* __restrict__ ao, const unsigned short* __restrict__ wp,
    float* __restrict__ out, const float* __restrict__ bias) {
  __shared__ __align__(16) unsigned short Ab[2 * 4096];
  __shared__ __align__(16) unsigned short Bb[2 * 8192];
  const int tid = threadIdx.x;
  const int w = tid >> 6, lane = tid & 63, quad = lane >> 4, id15 = lane & 15;
  const int wm = (w >> 1) << 5, wn = (w & 1) << 6;
  const int id = blockIdx.x;
  const int xcd = id & 7, slot = id >> 3;
  const int n0 = (slot % 6) << 7;
  const int m0 = (xcd * 16 + slot / 6) << 6;

  const int wb = tid & 192;
  const unsigned short* ap[2];
  int adst[2];
#pragma unroll
  for (int s = 0; s < 2; ++s) {
    int g = s * 256 + tid;
    int row = g >> 3;                      // 0..63
    int gs = (g & 7) ^ (row & 7);
    ap[s] = ao + (size_t)(m0 + row) * C_ + gs * 8;
    adst[s] = (s * 256 + wb) * 8;
  }
  const unsigned short* bp[4];
  int bdst[4];
#pragma unroll
  for (int s = 0; s < 4; ++s) {
    int g = s * 256 + tid;
    int row = g >> 3;                      // 0..127
    int gs = (g & 7) ^ (row & 7);
    bp[s] = wp + (size_t)(n0 + row) * C_ + gs * 8;
    bdst[s] = (s * 256 + wb) * 8;
  }
  auto issue = [&](int p, int si) {
    int kt = (si >= 12 ? si - 12 : si) * 64;
#pragma unroll
    for (int s = 0; s < 2; ++s) async16(ap[s] + kt, Ab + p * 4096 + adst[s]);
#pragma unroll
    for (int s = 0; s < 4; ++s) async16(bp[s] + kt, Bb + p * 8192 + bdst[s]);
  };
  issue(0, 0);
  issue(1, 1);
  const int sw0 = (quad ^ (id15 & 7)) * 8;
  const int sw1 = ((4 + quad) ^ (id15 & 7)) * 8;

  f32x4 acc[2][4] = {};
  for (int si = 0; si < 12; ++si) {
    const int p = si & 1;
    __builtin_amdgcn_sched_barrier(0);
    __builtin_amdgcn_s_waitcnt(WAIT_VM6);
    __builtin_amdgcn_s_barrier();
    __builtin_amdgcn_sched_barrier(0);

    const unsigned short* Ap = Ab + p * 4096;
    const unsigned short* Bp = Bb + p * 8192;
#pragma unroll
    for (int kk = 0; kk < 2; ++kk) {
      const int sw = kk ? sw1 : sw0;
      bf16x8 af[2], bfr[4];
#pragma unroll
      for (int i = 0; i < 2; ++i)
        af[i]  = ldb8(Ap + (wm + i * 16 + id15) * 64 + sw);
#pragma unroll
      for (int j = 0; j < 4; ++j)
        bfr[j] = ldb8(Bp + (wn + j * 16 + id15) * 64 + sw);
#pragma unroll
      for (int i = 0; i < 2; ++i)
#pragma unroll
        for (int j = 0; j < 4; ++j)
          acc[i][j] = mfma16(af[i], bfr[j], acc[i][j]);
    }

    __builtin_amdgcn_sched_barrier(0);
    __builtin_amdgcn_s_barrier();
    __builtin_amdgcn_sched_barrier(0);
    issue(p, si + 2);
  }
  __builtin_amdgcn_s_waitcnt(WAIT_VM0);

#pragma unroll
  for (int i = 0; i < 2; ++i) {
#pragma unroll
    for (int j = 0; j < 4; ++j) {
#pragma unroll
      for (int r = 0; r < 4; ++r) {
        int gm = m0 + wm + i * 16 + quad * 4 + r;
        int gn = n0 + wn + j * 16 + id15;
        out[(size_t)gm * C_ + gn] = acc[i][j][r] + bias[gn];
      }
    }
  }
}

// ---------------- Flash attention: S^T, exp2, MFMA-lsum, async double-buffer -------
// K/V staged via async16 into XOR-swizzled 64x64 tiles (2-way reads = free),
// double-buffered; partial vmcnt(4) waits keep next chunk's DMA in flight across
// the barriers (the R8 profile showed ~50% barrier-drain stall).
#define PSTR 72
__global__ __launch_bounds__(256, 3) void attn_kernel(
    const unsigned short* __restrict__ Q, const unsigned short* __restrict__ Kk,
    const unsigned short* __restrict__ Vt, unsigned short* __restrict__ O) {
  __shared__ __align__(16) unsigned short Kb[2][4096];
  __shared__ __align__(16) unsigned short Vb[2][4096];
  __shared__ __align__(16) unsigned short Pl[8][16 * PSTR];

  const int tid = threadIdx.x;
  const int w = tid >> 6, lane = tid & 63, quad = lane >> 4, id15 = lane & 15;
  const int id = blockIdx.x;
  const int xcd = id & 7, slot = id >> 3;
  const int bh = xcd * 6 + (slot >> 4);
  const int qt = slot & 15;
  const int b = bh / H_, h = bh % H_;
  const int q0 = qt * 128 + w * 32;

  bf16x8 qf[2][2];
#pragma unroll
  for (int rg = 0; rg < 2; ++rg)
#pragma unroll
    for (int kb = 0; kb < 2; ++kb)
      qf[rg][kb] = ldb8(Q + (size_t)(b * N_ + q0 + rg * 16 + id15) * C_ + h * 64 + kb * 32 + quad * 8);

  const uint4 onesu = {0x3F803F80u, 0x3F803F80u, 0x3F803F80u, 0x3F803F80u};
  const bf16x8 onesf = __builtin_bit_cast(bf16x8, onesu);

  f32x4 oacc[2][4] = {};
  f32x4 lacc[2] = {};

  const size_t kbase = (size_t)(b * N_) * C_ + h * 64;
  const size_t vbase = (size_t)(b * C_ + h * 64) * N_;

  // staging: granule G = s*256+tid -> row=G>>3 (0..63), slot=G&7, src g = slot^(row&7)
  const int wb = tid & 192;
  const unsigned short* kp[2];
  const unsigned short* vp[2];
  int dstq[2];
#pragma unroll
  for (int s = 0; s < 2; ++s) {
    int g = s * 256 + tid;
    int row = g >> 3;
    int gs = (g & 7) ^ (row & 7);
    kp[s] = Kk + kbase + (size_t)row * C_ + gs * 8;
    vp[s] = Vt + vbase + (size_t)row * N_ + gs * 8;
    dstq[s] = (s * 256 + wb) * 8;
  }
  auto issue = [&](int p, int ci) {
    int kc = (ci & 31) * 64;
    async16(kp[0] + (size_t)kc * C_, &Kb[p][dstq[0]]);
    async16(kp[1] + (size_t)kc * C_, &Kb[p][dstq[1]]);
    async16(vp[0] + kc, &Vb[p][dstq[0]]);
    async16(vp[1] + kc, &Vb[p][dstq[1]]);
  };
  issue(0, 0);
  issue(1, 1);
  const int sw0 = (quad ^ (id15 & 7)) * 8;
  const int sw1 = ((4 + quad) ^ (id15 & 7)) * 8;
  const int r64 = id15 * 64;

  unsigned short* Plw0 = &Pl[w * 2 + 0][0];
  unsigned short* Plw1 = &Pl[w * 2 + 1][0];

  for (int ci = 0; ci < 32; ++ci) {
    const int p = ci & 1;
    __builtin_amdgcn_sched_barrier(0);
    __builtin_amdgcn_s_waitcnt(WAIT_VM4);
    __builtin_amdgcn_s_barrier();
    __builtin_amdgcn_sched_barrier(0);

    const unsigned short* Kp = &Kb[p][0];
    const unsigned short* Vp = &Vb[p][0];

    // Phase 1: S^T (K-frags shared across both row-groups)
    f32x4 sA[4], sB[4];
#pragma unroll
    for (int cb = 0; cb < 4; ++cb) {
      f32x4 a = {}, c = {};
      const unsigned short* kr = Kp + cb * 1024 + r64;
      bf16x8 kf0 = ldb8(kr + sw0);
      a = mfma16(kf0, qf[0][0], a);
      c = mfma16(kf0, qf[1][0], c);
      bf16x8 kf1 = ldb8(kr + sw1);
      a = mfma16(kf1, qf[0][1], a);
      c = mfma16(kf1, qf[1][1], c);
      sA[cb] = a; sB[cb] = c;
    }

    // Phase 2: exp2 + truncate-pack + P write (wave-private LDS)
#pragma unroll
    for (int rg = 0; rg < 2; ++rg) {
      f32x4* s4 = (rg == 0) ? sA : sB;
      unsigned short* Plw = (rg == 0) ? Plw0 : Plw1;
#pragma unroll
      for (int cb = 0; cb < 4; ++cb) {
        unsigned p0 = __builtin_bit_cast(unsigned, exp2f(s4[cb][0]));
        unsigned p1 = __builtin_bit_cast(unsigned, exp2f(s4[cb][1]));
        unsigned p2 = __builtin_bit_cast(unsigned, exp2f(s4[cb][2]));
        unsigned p3 = __builtin_bit_cast(unsigned, exp2f(s4[cb][3]));
        uint2 u;
        u.x = __builtin_amdgcn_perm(p1, p0, 0x07060302u);
        u.y = __builtin_amdgcn_perm(p3, p2, 0x07060302u);
        *(uint2*)&Plw[id15 * PSTR + cb * 16 + quad * 4] = u;
      }
    }

    // Phase 3: P fragments (A-operand)
    bf16x8 pf[2][2];
#pragma unroll
    for (int kb = 0; kb < 2; ++kb) {
      pf[0][kb] = ldb8(&Plw0[id15 * PSTR + kb * 32 + quad * 8]);
      pf[1][kb] = ldb8(&Plw1[id15 * PSTR + kb * 32 + quad * 8]);
    }

    // Phase 4: ones-MFMA lsum + PV (V-frags shared)
#pragma unroll
    for (int kb = 0; kb < 2; ++kb) {
      lacc[0] = mfma16(pf[0][kb], onesf, lacc[0]);
      lacc[1] = mfma16(pf[1][kb], onesf, lacc[1]);
    }
#pragma unroll
    for (int db = 0; db < 4; ++db) {
      const unsigned short* vr = Vp + db * 1024 + r64;
      bf16x8 vf0 = ldb8(vr + sw0);
      oacc[0][db] = mfma16(pf[0][0], vf0, oacc[0][db]);
      oacc[1][db] = mfma16(pf[1][0], vf0, oacc[1][db]);
      bf16x8 vf1 = ldb8(vr + sw1);
      oacc[0][db] = mfma16(pf[0][1], vf1, oacc[0][db]);
      oacc[1][db] = mfma16(pf[1][1], vf1, oacc[1][db]);
    }

    __builtin_amdgcn_sched_barrier(0);
    __builtin_amdgcn_s_barrier();
    __builtin_amdgcn_sched_barrier(0);
    issue(p, ci + 2);             // ci>=30 wraps to chunks 0/1 (L2-hot dummy)
  }
  __builtin_amdgcn_s_waitcnt(WAIT_VM0);

  // Epilogue: lacc reg r holds l(row=quad*4+r) — same rows as oacc regs.
#pragma unroll
  for (int rg = 0; rg < 2; ++rg) {
#pragma unroll
    for (int r = 0; r < 4; ++r) {
      float linv = 1.0f / lacc[rg][r];
      int n = q0 + rg * 16 + quad * 4 + r;
#pragma unroll
      for (int db = 0; db < 4; ++db)
        O[(size_t)(b * N_ + n) * C_ + h * 64 + db * 16 + id15] = (unsigned short)f2bs(oacc[rg][db][r] * linv);
    }
  }
}

extern "C" void kernel_launch(void* const* d_in, const int* in_sizes, int n_in,
                              void* d_out, int out_size, void* d_ws, size_t ws_size,
                              hipStream_t stream) {
  const float* x_q = (const float*)d_in[0];
  const float* x_k = (const float*)d_in[1];
  const float* x_v = (const float*)d_in[2];
  const float* x_u = (const float*)d_in[3];
  const float* Wq  = (const float*)d_in[4];
  const float* Wk  = (const float*)d_in[5];
  const float* Wv  = (const float*)d_in[6];
  const float* Wp  = (const float*)d_in[7];
  const float* bp  = (const float*)d_in[8];

  char* ws = (char*)d_ws;
  size_t off = 0;
  auto alloc = [&](size_t bytes) {
    char* p = ws + off;
    off += (bytes + 255) & ~(size_t)255;
    return p;
  };
  unsigned short* wq16 = (unsigned short*)alloc((size_t)C_ * C_ * 2);
  unsigned short* wk16 = (unsigned short*)alloc((size_t)C_ * C_ * 2);
  unsigned short* wv16 = (unsigned short*)alloc((size_t)C_ * C_ * 2);
  unsigned short* wp16 = (unsigned short*)alloc((size_t)C_ * C_ * 2);
  float*          ucp  = (float*)alloc((size_t)B_ * N_ * 4);
  unsigned short* xq16 = (unsigned short*)alloc((size_t)B_ * N_ * C_ * 2);
  unsigned short* xk16 = (unsigned short*)alloc((size_t)B_ * N_ * C_ * 2);
  unsigned short* xv16 = (unsigned short*)alloc((size_t)B_ * N_ * C_ * 2);
  unsigned short* q_s  = (unsigned short*)alloc((size_t)B_ * N_ * C_ * 2);
  unsigned short* k_s  = (unsigned short*)alloc((size_t)B_ * N_ * C_ * 2);
  unsigned short* vT   = (unsigned short*)alloc((size_t)B_ * N_ * C_ * 2);
  unsigned short* ao   = (unsigned short*)alloc((size_t)B_ * N_ * C_ * 2);

  prep_kernel<<<dim3(22784), 256, 0, stream>>>(x_q, x_k, x_v, x_u, Wq, Wk, Wv, Wp,
                                               xq16, xk16, xv16,
                                               wq16, wk16, wv16, wp16, ucp);
  gemm_qkv<<<dim3(1152), 256, 0, stream>>>(xq16, xk16, xv16, wq16, wk16, wv16,
                                           q_s, k_s, vT, ucp);
  attn_kernel<<<dim3(768), 256, 0, stream>>>(q_s, k_s, vT, ao);
  gemm_out<<<dim3(768), 256, 0, stream>>>(ao, wp16, (float*)d_out, bp);
}